// Round 1
// baseline (1127.078 us; speedup 1.0000x reference)
//
#include <hip/hip_runtime.h>
#include <hip/hip_bf16.h>

// Problem constants (from reference)
#define NNODES 10000
#define NEDGES 320000
#define INF_   1280
#define HID_   128
#define HEADS_ 4
#define OUTF_  500
#define HC_    512          // HEADS_*HID_
#define NEG_SLOPE 0.2f
#define BN_EPS 1e-5f

// ---------------------------------------------------------------------------
// utility kernels
// ---------------------------------------------------------------------------
__global__ void zero_kernel(float* __restrict__ p, size_t n) {
    size_t i = (size_t)blockIdx.x * blockDim.x + threadIdx.x;
    size_t stride = (size_t)gridDim.x * blockDim.x;
    for (; i < n; i += stride) p[i] = 0.0f;
}

__global__ void copy_int_kernel(const int* __restrict__ src, int* __restrict__ dst, int n) {
    int i = blockIdx.x * blockDim.x + threadIdx.x;
    if (i < n) dst[i] = src[i];
}

// ---------------------------------------------------------------------------
// CSR build (by destination) — edges are identical across layers, built once
// ---------------------------------------------------------------------------
__global__ void count_kernel(const int* __restrict__ dst, int* __restrict__ counts, int E) {
    int e = blockIdx.x * blockDim.x + threadIdx.x;
    if (e < E) atomicAdd(&counts[dst[e]], 1);
}

__global__ void scan_kernel(const int* __restrict__ counts, int* __restrict__ offsets, int n) {
    __shared__ int tmp[1024];
    int tid = threadIdx.x;
    int carry = 0;
    int nchunk = (n + 1023) / 1024;
    for (int ch = 0; ch < nchunk; ++ch) {
        int i = ch * 1024 + tid;
        int v = (i < n) ? counts[i] : 0;
        tmp[tid] = v;
        __syncthreads();
        for (int off = 1; off < 1024; off <<= 1) {
            int t = (tid >= off) ? tmp[tid - off] : 0;
            __syncthreads();
            tmp[tid] += t;
            __syncthreads();
        }
        if (i < n) offsets[i] = carry + tmp[tid] - v;  // exclusive scan
        carry += tmp[1023];
        __syncthreads();
    }
    if (tid == 0) offsets[n] = carry;
}

__global__ void scatter_kernel(const int* __restrict__ src, const int* __restrict__ dst,
                               int* __restrict__ cursor, int* __restrict__ esrc, int E) {
    int e = blockIdx.x * blockDim.x + threadIdx.x;
    if (e < E) {
        int p = atomicAdd(&cursor[dst[e]], 1);
        esrc[p] = src[e];
    }
}

// ---------------------------------------------------------------------------
// fp32 tiled GEMM: C[M,N] = A[M,K] @ B[K,N]   (K always multiple of 16)
// 64x64 tile, 256 threads, 4x4 micro-tile per thread
// ---------------------------------------------------------------------------
#define BM 64
#define BN 64
#define BK 16

__global__ __launch_bounds__(256) void gemm_kernel(const float* __restrict__ A,
                                                   const float* __restrict__ B,
                                                   float* __restrict__ C,
                                                   int M, int K, int N) {
    __shared__ __align__(16) float As[BK][BM];   // transposed: As[k][m]
    __shared__ __align__(16) float Bs[BK][BN];
    int tid = threadIdx.x;
    int tx = tid & 15;     // col group
    int ty = tid >> 4;     // row group
    int m0 = blockIdx.y * BM;
    int n0 = blockIdx.x * BN;

    float acc[4][4];
#pragma unroll
    for (int i = 0; i < 4; ++i)
#pragma unroll
        for (int j = 0; j < 4; ++j) acc[i][j] = 0.0f;

    int la_m = tid >> 2;          // 0..63
    int la_k = (tid & 3) * 4;     // 0,4,8,12
    int lb_k = tid >> 4;          // 0..15
    int lb_n = (tid & 15) * 4;    // 0..60

    for (int k0 = 0; k0 < K; k0 += BK) {
        // A tile: rows m0..m0+63, cols k0..k0+15
        int am = m0 + la_m;
        float4 av = make_float4(0.f, 0.f, 0.f, 0.f);
        if (am < M) av = *(const float4*)(A + (size_t)am * K + k0 + la_k);
        As[la_k + 0][la_m] = av.x;
        As[la_k + 1][la_m] = av.y;
        As[la_k + 2][la_m] = av.z;
        As[la_k + 3][la_m] = av.w;
        // B tile: rows k0..k0+15, cols n0..n0+63
        int bn = n0 + lb_n;
        float4 bv = make_float4(0.f, 0.f, 0.f, 0.f);
        const float* brow = B + (size_t)(k0 + lb_k) * N;
        if (bn + 3 < N) {
            bv = *(const float4*)(brow + bn);
        } else {
            if (bn + 0 < N) bv.x = brow[bn + 0];
            if (bn + 1 < N) bv.y = brow[bn + 1];
            if (bn + 2 < N) bv.z = brow[bn + 2];
            if (bn + 3 < N) bv.w = brow[bn + 3];
        }
        *(float4*)&Bs[lb_k][lb_n] = bv;
        __syncthreads();

#pragma unroll
        for (int k = 0; k < BK; ++k) {
            float4 a = *(const float4*)&As[k][ty * 4];
            float4 b = *(const float4*)&Bs[k][tx * 4];
            acc[0][0] += a.x * b.x; acc[0][1] += a.x * b.y; acc[0][2] += a.x * b.z; acc[0][3] += a.x * b.w;
            acc[1][0] += a.y * b.x; acc[1][1] += a.y * b.y; acc[1][2] += a.y * b.z; acc[1][3] += a.y * b.w;
            acc[2][0] += a.z * b.x; acc[2][1] += a.z * b.y; acc[2][2] += a.z * b.z; acc[2][3] += a.z * b.w;
            acc[3][0] += a.w * b.x; acc[3][1] += a.w * b.y; acc[3][2] += a.w * b.z; acc[3][3] += a.w * b.w;
        }
        __syncthreads();
    }

#pragma unroll
    for (int i = 0; i < 4; ++i) {
        int m = m0 + ty * 4 + i;
        if (m >= M) continue;
#pragma unroll
        for (int j = 0; j < 4; ++j) {
            int n = n0 + tx * 4 + j;
            if (n < N) C[(size_t)m * N + n] = acc[i][j];
        }
    }
}

// ---------------------------------------------------------------------------
// attention logits: s[i,h] = sum_c xp[i,h,c]*a_src[h,c];  d likewise
// block = 512 threads = H groups of G (G = 512/H, power of two >= C)
// ---------------------------------------------------------------------------
__global__ __launch_bounds__(512) void logits_kernel(const float* __restrict__ xp,
                                                     const float* __restrict__ a_src,
                                                     const float* __restrict__ a_dst,
                                                     float* __restrict__ s,
                                                     float* __restrict__ d,
                                                     int H, int C) {
    int node = blockIdx.x;
    int tid = threadIdx.x;
    int G = 512 / H;
    int h = tid / G;
    int c = tid % G;
    int HC = H * C;
    float vs = 0.f, vd = 0.f;
    if (c < C) {
        float v = xp[(size_t)node * HC + h * C + c];
        vs = v * a_src[h * C + c];
        vd = v * a_dst[h * C + c];
    }
    __shared__ float rs[512];
    __shared__ float rd[512];
    rs[tid] = vs; rd[tid] = vd;
    __syncthreads();
    for (int off = G >> 1; off > 0; off >>= 1) {
        if (c < off) { rs[tid] += rs[tid + off]; rd[tid] += rd[tid + off]; }
        __syncthreads();
    }
    if (c == 0) { s[node * H + h] = rs[tid]; d[node * H + h] = rd[tid]; }
}

// ---------------------------------------------------------------------------
// fused edge phase: online-softmax attention + aggregation, one block per dst
// thread = (head, channel). Self-loop handled implicitly (src = dst).
// ---------------------------------------------------------------------------
__global__ __launch_bounds__(512) void aggregate_kernel(const float* __restrict__ xp,
                                                        const float* __restrict__ s,
                                                        const float* __restrict__ dlog,
                                                        const int* __restrict__ offsets,
                                                        const int* __restrict__ esrc,
                                                        const float* __restrict__ bias,
                                                        float* __restrict__ out,
                                                        int H, int C) {
    int dst = blockIdx.x;
    int tid = threadIdx.x;
    int HC = H * C;
    if (tid >= HC) return;  // no __syncthreads below
    int h = tid / C;
    int c = tid - h * C;
    float dh = dlog[dst * H + h];

    // self-loop initializes the online softmax state
    float m = s[dst * H + h] + dh;
    m = (m >= 0.f) ? m : NEG_SLOPE * m;
    float acc = xp[(size_t)dst * HC + h * C + c];
    float z = 1.0f;

    int e0 = offsets[dst], e1 = offsets[dst + 1];
    for (int j = e0; j < e1; ++j) {
        int src = esrc[j];
        float e = s[src * H + h] + dh;
        e = (e >= 0.f) ? e : NEG_SLOPE * e;
        float mn = fmaxf(m, e);
        float so = __expf(m - mn);
        float w = __expf(e - mn);
        acc = acc * so + w * xp[(size_t)src * HC + h * C + c];
        z = z * so + w;
        m = mn;
    }
    out[(size_t)dst * HC + h * C + c] = acc / z + bias[h * C + c];
}

// ---------------------------------------------------------------------------
// BatchNorm (training-mode normalization, biased var) + ELU
// ---------------------------------------------------------------------------
__global__ __launch_bounds__(512) void bn_stats_kernel(const float* __restrict__ h,
                                                       float* __restrict__ sums,
                                                       float* __restrict__ sumsq,
                                                       int Nrows, int Ncols) {
    int c = threadIdx.x;  // Ncols == 512 == blockDim
    float sm = 0.f, sq = 0.f;
    for (int r = blockIdx.x; r < Nrows; r += gridDim.x) {
        float v = h[(size_t)r * Ncols + c];
        sm += v;
        sq += v * v;
    }
    atomicAdd(&sums[c], sm);
    atomicAdd(&sumsq[c], sq);
}

__global__ __launch_bounds__(512) void bn_finalize_kernel(const float* __restrict__ sums,
                                                          const float* __restrict__ sumsq,
                                                          const float* __restrict__ gamma,
                                                          const float* __restrict__ beta,
                                                          float* __restrict__ scale,
                                                          float* __restrict__ shift,
                                                          int Nrows, int Ncols) {
    int c = threadIdx.x;
    if (c < Ncols) {
        float mu = sums[c] / (float)Nrows;
        float var = sumsq[c] / (float)Nrows - mu * mu;
        float sc = gamma[c] * rsqrtf(var + BN_EPS);
        scale[c] = sc;
        shift[c] = beta[c] - mu * sc;
    }
}

__global__ void bn_apply_elu_kernel(float* __restrict__ h,
                                    const float* __restrict__ scale,
                                    const float* __restrict__ shift,
                                    size_t total) {
    size_t i = (size_t)blockIdx.x * blockDim.x + threadIdx.x;
    size_t stride = (size_t)gridDim.x * blockDim.x;
    for (; i < total; i += stride) {
        int c = (int)(i & 511);  // Ncols = 512
        float v = h[i] * scale[c] + shift[c];
        h[i] = (v > 0.f) ? v : (__expf(v) - 1.0f);
    }
}

// ---------------------------------------------------------------------------
// launch
// ---------------------------------------------------------------------------
extern "C" void kernel_launch(void* const* d_in, const int* in_sizes, int n_in,
                              void* d_out, int out_size, void* d_ws, size_t ws_size,
                              hipStream_t stream) {
    const float* x      = (const float*)d_in[0];
    const int*   ei     = (const int*)d_in[1];
    const float* W1     = (const float*)d_in[2];
    const float* a_src1 = (const float*)d_in[3];
    const float* a_dst1 = (const float*)d_in[4];
    const float* b1     = (const float*)d_in[5];
    const float* g1     = (const float*)d_in[6];
    const float* be1    = (const float*)d_in[7];
    const float* W2     = (const float*)d_in[8];
    const float* a_src2 = (const float*)d_in[9];
    const float* a_dst2 = (const float*)d_in[10];
    const float* b2     = (const float*)d_in[11];
    const float* g2     = (const float*)d_in[12];
    const float* be2    = (const float*)d_in[13];
    const float* W3     = (const float*)d_in[14];
    const float* a_src3 = (const float*)d_in[15];
    const float* a_dst3 = (const float*)d_in[16];
    const float* b3     = (const float*)d_in[17];
    float* out = (float*)d_out;

    const int* e_src = ei;           // edge_index[0]
    const int* e_dst = ei + NEDGES;  // edge_index[1]

    // workspace layout
    float* xp      = (float*)d_ws;                 // 5,120,000
    float* h       = xp + (size_t)NNODES * HC_;    // 5,120,000
    float* s_log   = h + (size_t)NNODES * HC_;     // 40,000
    float* d_log   = s_log + NNODES * HEADS_;      // 40,000
    float* bns     = d_log + NNODES * HEADS_;      // 512
    float* bnss    = bns + HC_;                    // 512
    float* bnscale = bnss + HC_;                   // 512
    float* bnshift = bnscale + HC_;                // 512
    int*   counts  = (int*)(bnshift + HC_);        // 10,000
    int*   offsets = counts + NNODES;              // 10,001
    int*   cursor  = offsets + NNODES + 1;         // 10,000
    int*   esrc    = cursor + NNODES;              // 320,000

    // ---- CSR build (once; shared by all 3 layers) ----
    zero_kernel<<<64, 256, 0, stream>>>((float*)counts, NNODES);
    count_kernel<<<(NEDGES + 255) / 256, 256, 0, stream>>>(e_dst, counts, NEDGES);
    scan_kernel<<<1, 1024, 0, stream>>>(counts, offsets, NNODES);
    copy_int_kernel<<<(NNODES + 255) / 256, 256, 0, stream>>>(offsets, cursor, NNODES);
    scatter_kernel<<<(NEDGES + 255) / 256, 256, 0, stream>>>(e_src, e_dst, cursor, esrc, NEDGES);

    dim3 gemm_block(256);
    dim3 gemm_grid1((HC_ + BN - 1) / BN, (NNODES + BM - 1) / BM);

    // ---- Layer 1 ----
    gemm_kernel<<<gemm_grid1, gemm_block, 0, stream>>>(x, W1, xp, NNODES, INF_, HC_);
    logits_kernel<<<NNODES, 512, 0, stream>>>(xp, a_src1, a_dst1, s_log, d_log, HEADS_, HID_);
    aggregate_kernel<<<NNODES, 512, 0, stream>>>(xp, s_log, d_log, offsets, esrc, b1, h, HEADS_, HID_);
    // BN1 + ELU
    zero_kernel<<<4, 256, 0, stream>>>(bns, 2 * HC_);
    bn_stats_kernel<<<64, 512, 0, stream>>>(h, bns, bnss, NNODES, HC_);
    bn_finalize_kernel<<<1, 512, 0, stream>>>(bns, bnss, g1, be1, bnscale, bnshift, NNODES, HC_);
    bn_apply_elu_kernel<<<2048, 256, 0, stream>>>(h, bnscale, bnshift, (size_t)NNODES * HC_);

    // ---- Layer 2 ----
    gemm_kernel<<<gemm_grid1, gemm_block, 0, stream>>>(h, W2, xp, NNODES, HC_, HC_);
    logits_kernel<<<NNODES, 512, 0, stream>>>(xp, a_src2, a_dst2, s_log, d_log, HEADS_, HID_);
    aggregate_kernel<<<NNODES, 512, 0, stream>>>(xp, s_log, d_log, offsets, esrc, b2, h, HEADS_, HID_);
    // BN2 + ELU
    zero_kernel<<<4, 256, 0, stream>>>(bns, 2 * HC_);
    bn_stats_kernel<<<64, 512, 0, stream>>>(h, bns, bnss, NNODES, HC_);
    bn_finalize_kernel<<<1, 512, 0, stream>>>(bns, bnss, g2, be2, bnscale, bnshift, NNODES, HC_);
    bn_apply_elu_kernel<<<2048, 256, 0, stream>>>(h, bnscale, bnshift, (size_t)NNODES * HC_);

    // ---- Layer 3 (H=1, C=500, output straight to d_out) ----
    dim3 gemm_grid3((OUTF_ + BN - 1) / BN, (NNODES + BM - 1) / BM);
    gemm_kernel<<<gemm_grid3, gemm_block, 0, stream>>>(h, W3, xp, NNODES, HC_, OUTF_);
    logits_kernel<<<NNODES, 512, 0, stream>>>(xp, a_src3, a_dst3, s_log, d_log, 1, OUTF_);
    aggregate_kernel<<<NNODES, 512, 0, stream>>>(xp, s_log, d_log, offsets, esrc, b3, out, 1, OUTF_);
}

// Round 2
// 672.150 us; speedup vs baseline: 1.6768x; 1.6768x over previous
//
#include <hip/hip_runtime.h>
#include <hip/hip_bf16.h>

// Problem constants (from reference)
#define NNODES 10000
#define NEDGES 320000
#define INF_   1280
#define HID_   128
#define HEADS_ 4
#define OUTF_  500
#define HC_    512          // HEADS_*HID_
#define NEG_SLOPE 0.2f
#define BN_EPS 1e-5f

typedef __attribute__((ext_vector_type(8))) short short8x;
typedef __attribute__((ext_vector_type(4))) float f32x4;
typedef unsigned short ushort_t;
typedef unsigned int uint_t;

__device__ __forceinline__ ushort_t f2bf(float f) {
    uint_t u = __float_as_uint(f);
    u = (u + 0x7fffu + ((u >> 16) & 1u)) >> 16;   // round-to-nearest-even
    return (ushort_t)u;
}
__device__ __forceinline__ float bf_lo(uint_t p) { return __uint_as_float(p << 16); }
__device__ __forceinline__ float bf_hi(uint_t p) { return __uint_as_float(p & 0xffff0000u); }

// ---------------------------------------------------------------------------
// utility kernels
// ---------------------------------------------------------------------------
__global__ void zero_kernel(float* __restrict__ p, size_t n) {
    size_t i = (size_t)blockIdx.x * blockDim.x + threadIdx.x;
    size_t stride = (size_t)gridDim.x * blockDim.x;
    for (; i < n; i += stride) p[i] = 0.0f;
}

__global__ void copy_int_kernel(const int* __restrict__ src, int* __restrict__ dst, int n) {
    int i = blockIdx.x * blockDim.x + threadIdx.x;
    if (i < n) dst[i] = src[i];
}

// fp32 -> bf16 (flat)
__global__ void conv_bf16_kernel(const float* __restrict__ in, ushort_t* __restrict__ out, int n) {
    int i = blockIdx.x * blockDim.x + threadIdx.x;
    if (i < n) out[i] = f2bf(in[i]);
}

// fp32 W[K][N] -> bf16 Wt[N][K]  (write-coalesced)
__global__ void transconv_kernel(const float* __restrict__ W, ushort_t* __restrict__ Wt, int K, int N) {
    int i = blockIdx.x * blockDim.x + threadIdx.x;
    if (i < N * K) {
        int n = i / K;
        int k = i - n * K;
        Wt[i] = f2bf(W[(size_t)k * N + n]);
    }
}

// ---------------------------------------------------------------------------
// CSR build (by destination) — edges are identical across layers, built once
// ---------------------------------------------------------------------------
__global__ void count_kernel(const int* __restrict__ dst, int* __restrict__ counts, int E) {
    int e = blockIdx.x * blockDim.x + threadIdx.x;
    if (e < E) atomicAdd(&counts[dst[e]], 1);
}

__global__ void scan_kernel(const int* __restrict__ counts, int* __restrict__ offsets, int n) {
    __shared__ int tmp[1024];
    int tid = threadIdx.x;
    int carry = 0;
    int nchunk = (n + 1023) / 1024;
    for (int ch = 0; ch < nchunk; ++ch) {
        int i = ch * 1024 + tid;
        int v = (i < n) ? counts[i] : 0;
        tmp[tid] = v;
        __syncthreads();
        for (int off = 1; off < 1024; off <<= 1) {
            int t = (tid >= off) ? tmp[tid - off] : 0;
            __syncthreads();
            tmp[tid] += t;
            __syncthreads();
        }
        if (i < n) offsets[i] = carry + tmp[tid] - v;  // exclusive scan
        carry += tmp[1023];
        __syncthreads();
    }
    if (tid == 0) offsets[n] = carry;
}

__global__ void scatter_kernel(const int* __restrict__ src, const int* __restrict__ dst,
                               int* __restrict__ cursor, int* __restrict__ esrc, int E) {
    int e = blockIdx.x * blockDim.x + threadIdx.x;
    if (e < E) {
        int p = atomicAdd(&cursor[dst[e]], 1);
        esrc[p] = src[e];
    }
}

// ---------------------------------------------------------------------------
// bf16 MFMA GEMM: C[M,N] = A[M,K] @ B[K,N]
//   A row-major bf16 [M][K]; B given pre-transposed: Wt[N][K] bf16.
//   64x64 tile, BK=32, 256 threads = 4 waves, each wave a 32x32 quadrant
//   (2x2 grid of 16x16x32 MFMAs). K must be a multiple of 32.
// Fragment layouts (HW-verified per guide):
//   A-frag: A[m=lane&15][k=quad*8+j]   B-frag: B[k=quad*8+j][n=lane&15]
//   C/D:    col=lane&15, row=quad*4+reg
// ---------------------------------------------------------------------------
#define LDT 40   // LDS row stride in bf16 units (padded; 80B keeps 16B align)

__global__ __launch_bounds__(256) void gemm_bf16_kernel(
    const ushort_t* __restrict__ A,    // [M][K] bf16
    const ushort_t* __restrict__ Bt,   // [N][K] bf16 (transposed weights)
    float* __restrict__ Cf,            // [M][N] fp32 or nullptr
    ushort_t* __restrict__ Cb,         // [M][N] bf16 or nullptr
    int M, int K, int N)
{
    __shared__ __align__(16) ushort_t As[64 * LDT];
    __shared__ __align__(16) ushort_t Bs[64 * LDT];

    int tid  = threadIdx.x;
    int lane = tid & 63;
    int w    = tid >> 6;
    int wm   = (w & 1) * 32;
    int wn   = (w >> 1) * 32;
    int quad = lane >> 4;
    int c16  = lane & 15;
    int m0 = blockIdx.y * 64;
    int n0 = blockIdx.x * 64;

    f32x4 acc[2][2];
#pragma unroll
    for (int i = 0; i < 2; ++i)
#pragma unroll
        for (int j = 0; j < 2; ++j)
#pragma unroll
            for (int r = 0; r < 4; ++r) acc[i][j][r] = 0.0f;

    // staging coords (both tiles are [row][k] with contiguous 16B chunks)
    int sr = tid >> 2;          // 0..63 row within tile
    int sk = (tid & 3) * 8;     // k chunk: 0,8,16,24

    for (int k0 = 0; k0 < K; k0 += 32) {
        uint4 av = make_uint4(0, 0, 0, 0);
        int gm = m0 + sr;
        if (gm < M) av = *(const uint4*)(A + (size_t)gm * K + k0 + sk);
        *(uint4*)&As[sr * LDT + sk] = av;

        uint4 bv = make_uint4(0, 0, 0, 0);
        int gn = n0 + sr;
        if (gn < N) bv = *(const uint4*)(Bt + (size_t)gn * K + k0 + sk);
        *(uint4*)&Bs[sr * LDT + sk] = bv;
        __syncthreads();

        short8x af0 = *(const short8x*)&As[(wm +      c16) * LDT + quad * 8];
        short8x af1 = *(const short8x*)&As[(wm + 16 + c16) * LDT + quad * 8];
        short8x bf0 = *(const short8x*)&Bs[(wn +      c16) * LDT + quad * 8];
        short8x bf1 = *(const short8x*)&Bs[(wn + 16 + c16) * LDT + quad * 8];

        acc[0][0] = __builtin_amdgcn_mfma_f32_16x16x32_bf16(af0, bf0, acc[0][0], 0, 0, 0);
        acc[0][1] = __builtin_amdgcn_mfma_f32_16x16x32_bf16(af0, bf1, acc[0][1], 0, 0, 0);
        acc[1][0] = __builtin_amdgcn_mfma_f32_16x16x32_bf16(af1, bf0, acc[1][0], 0, 0, 0);
        acc[1][1] = __builtin_amdgcn_mfma_f32_16x16x32_bf16(af1, bf1, acc[1][1], 0, 0, 0);
        __syncthreads();
    }

#pragma unroll
    for (int mt = 0; mt < 2; ++mt) {
#pragma unroll
        for (int nt = 0; nt < 2; ++nt) {
#pragma unroll
            for (int r = 0; r < 4; ++r) {
                int row = m0 + wm + mt * 16 + quad * 4 + r;
                int col = n0 + wn + nt * 16 + c16;
                if (row < M && col < N) {
                    float v = acc[mt][nt][r];
                    if (Cf) Cf[(size_t)row * N + col] = v;
                    if (Cb) Cb[(size_t)row * N + col] = f2bf(v);
                }
            }
        }
    }
}

// ---------------------------------------------------------------------------
// attention logits from bf16 xp (packed pairs). block=256; group G=256/H.
// ---------------------------------------------------------------------------
__global__ __launch_bounds__(256) void logits_bf16_kernel(
    const uint_t* __restrict__ xpb,     // [node][HCp] packed 2xbf16
    const float* __restrict__ a_src, const float* __restrict__ a_dst,
    float* __restrict__ s, float* __restrict__ d,
    int H, int C, int Cpair)
{
    int node = blockIdx.x;
    int tid = threadIdx.x;
    int G = 256 / H;
    int h = tid / G;
    int cp = tid - h * G;
    int HCp = H * Cpair;
    float vs = 0.f, vd = 0.f;
    if (cp < Cpair) {
        uint_t p = xpb[(size_t)node * HCp + h * Cpair + cp];
        float f0 = bf_lo(p), f1 = bf_hi(p);
        int c = cp * 2;
        vs = f0 * a_src[h * C + c] + f1 * a_src[h * C + c + 1];
        vd = f0 * a_dst[h * C + c] + f1 * a_dst[h * C + c + 1];
    }
    __shared__ float rs[256];
    __shared__ float rd[256];
    rs[tid] = vs; rd[tid] = vd;
    __syncthreads();
    for (int off = G >> 1; off > 0; off >>= 1) {
        if (cp < off) { rs[tid] += rs[tid + off]; rd[tid] += rd[tid + off]; }
        __syncthreads();
    }
    if (cp == 0) { s[node * H + h] = rs[tid]; d[node * H + h] = rd[tid]; }
}

// ---------------------------------------------------------------------------
// fused edge phase (bf16 xp): online-softmax attention + aggregation.
// one block of 256 per dst node; thread = channel pair. Output fp32.
// ---------------------------------------------------------------------------
__global__ __launch_bounds__(256) void aggregate_bf16_kernel(
    const uint_t* __restrict__ xpb,     // [node][HCp] packed 2xbf16
    const float* __restrict__ s, const float* __restrict__ dlog,
    const int* __restrict__ offsets, const int* __restrict__ esrc,
    const float* __restrict__ bias,
    float* __restrict__ out,
    int H, int C, int Cpair)
{
    int dst = blockIdx.x;
    int tid = threadIdx.x;
    int HCp = H * Cpair;
    if (tid >= HCp) return;   // no __syncthreads below
    int h = tid / Cpair;
    int cp = tid - h * Cpair;
    float dh = dlog[dst * H + h];

    // self-loop initializes the online-softmax state
    float m = s[dst * H + h] + dh;
    m = (m >= 0.f) ? m : NEG_SLOPE * m;
    uint_t p = xpb[(size_t)dst * HCp + tid];
    float acc0 = bf_lo(p);
    float acc1 = bf_hi(p);
    float z = 1.0f;

    int e0 = offsets[dst], e1 = offsets[dst + 1];
    for (int j = e0; j < e1; ++j) {
        int src = esrc[j];
        float e = s[src * H + h] + dh;
        e = (e >= 0.f) ? e : NEG_SLOPE * e;
        float mn = fmaxf(m, e);
        float so = __expf(m - mn);
        float wgt = __expf(e - mn);
        uint_t q = xpb[(size_t)src * HCp + tid];
        acc0 = acc0 * so + wgt * bf_lo(q);
        acc1 = acc1 * so + wgt * bf_hi(q);
        z = z * so + wgt;
        m = mn;
    }
    int c = cp * 2;
    size_t base = (size_t)dst * (H * C) + h * C + c;
    float inv = 1.0f / z;
    out[base]     = acc0 * inv + bias[h * C + c];
    out[base + 1] = acc1 * inv + bias[h * C + c + 1];
}

// ---------------------------------------------------------------------------
// BatchNorm (training-mode normalization, biased var) + ELU -> bf16
// ---------------------------------------------------------------------------
__global__ __launch_bounds__(512) void bn_stats_kernel(const float* __restrict__ h,
                                                       float* __restrict__ sums,
                                                       float* __restrict__ sumsq,
                                                       int Nrows, int Ncols) {
    int c = threadIdx.x;  // Ncols == 512 == blockDim
    float sm = 0.f, sq = 0.f;
    for (int r = blockIdx.x; r < Nrows; r += gridDim.x) {
        float v = h[(size_t)r * Ncols + c];
        sm += v;
        sq += v * v;
    }
    atomicAdd(&sums[c], sm);
    atomicAdd(&sumsq[c], sq);
}

__global__ __launch_bounds__(512) void bn_finalize_kernel(const float* __restrict__ sums,
                                                          const float* __restrict__ sumsq,
                                                          const float* __restrict__ gamma,
                                                          const float* __restrict__ beta,
                                                          float* __restrict__ scale,
                                                          float* __restrict__ shift,
                                                          int Nrows, int Ncols) {
    int c = threadIdx.x;
    if (c < Ncols) {
        float mu = sums[c] / (float)Nrows;
        float var = sumsq[c] / (float)Nrows - mu * mu;
        float sc = gamma[c] * rsqrtf(var + BN_EPS);
        scale[c] = sc;
        shift[c] = beta[c] - mu * sc;
    }
}

// h fp32 [N][512] -> hbf packed bf16 pairs [N][256]
__global__ void bn_apply_elu_bf16_kernel(const float* __restrict__ h,
                                         const float* __restrict__ scale,
                                         const float* __restrict__ shift,
                                         uint_t* __restrict__ hbf,
                                         int npairs) {
    int i = blockIdx.x * blockDim.x + threadIdx.x;
    if (i < npairs) {
        int c0 = (i & 255) * 2;   // Ncols = 512
        float2 hv = ((const float2*)h)[i];
        float v0 = hv.x * scale[c0]     + shift[c0];
        float v1 = hv.y * scale[c0 + 1] + shift[c0 + 1];
        v0 = (v0 > 0.f) ? v0 : (__expf(v0) - 1.0f);
        v1 = (v1 > 0.f) ? v1 : (__expf(v1) - 1.0f);
        hbf[i] = ((uint_t)f2bf(v1) << 16) | (uint_t)f2bf(v0);
    }
}

// ---------------------------------------------------------------------------
// launch
// ---------------------------------------------------------------------------
extern "C" void kernel_launch(void* const* d_in, const int* in_sizes, int n_in,
                              void* d_out, int out_size, void* d_ws, size_t ws_size,
                              hipStream_t stream) {
    const float* x      = (const float*)d_in[0];
    const int*   ei     = (const int*)d_in[1];
    const float* W1     = (const float*)d_in[2];
    const float* a_src1 = (const float*)d_in[3];
    const float* a_dst1 = (const float*)d_in[4];
    const float* b1     = (const float*)d_in[5];
    const float* g1     = (const float*)d_in[6];
    const float* be1    = (const float*)d_in[7];
    const float* W2     = (const float*)d_in[8];
    const float* a_src2 = (const float*)d_in[9];
    const float* a_dst2 = (const float*)d_in[10];
    const float* b2     = (const float*)d_in[11];
    const float* g2     = (const float*)d_in[12];
    const float* be2    = (const float*)d_in[13];
    const float* W3     = (const float*)d_in[14];
    const float* a_src3 = (const float*)d_in[15];
    const float* a_dst3 = (const float*)d_in[16];
    const float* b3     = (const float*)d_in[17];
    float* out = (float*)d_out;

    const int* e_src = ei;           // edge_index[0]
    const int* e_dst = ei + NEDGES;  // edge_index[1]

    // ---- workspace layout (bytes) ----
    char* w = (char*)d_ws;
    // region 0: x_bf (12.8M ushort = 25.6MB), later reused as hbuf fp32 (20.48MB)
    ushort_t* x_bf = (ushort_t*)w;
    float*    hbuf = (float*)w;                              // alias: valid after L1 GEMM
    w += (size_t)NNODES * INF_ * sizeof(ushort_t);           // 25,600,000
    uint_t* xpb = (uint_t*)w;  w += (size_t)NNODES * HC_ * sizeof(ushort_t);   // 10,240,000
    uint_t* hbf = (uint_t*)w;  w += (size_t)NNODES * HC_ * sizeof(ushort_t);   // 10,240,000
    ushort_t* Wt1 = (ushort_t*)w; w += (size_t)INF_ * HC_ * sizeof(ushort_t);  // 1,310,720
    ushort_t* Wt2 = (ushort_t*)w; w += (size_t)HC_ * HC_ * sizeof(ushort_t);   //   524,288
    ushort_t* Wt3 = (ushort_t*)w; w += (size_t)HC_ * OUTF_ * sizeof(ushort_t); //   512,000
    float* s_log = (float*)w;  w += NNODES * HEADS_ * sizeof(float);
    float* d_log = (float*)w;  w += NNODES * HEADS_ * sizeof(float);
    float* bns   = (float*)w;  w += HC_ * sizeof(float);
    float* bnss  = (float*)w;  w += HC_ * sizeof(float);
    float* bnscale = (float*)w; w += HC_ * sizeof(float);
    float* bnshift = (float*)w; w += HC_ * sizeof(float);
    int* counts  = (int*)w;    w += NNODES * sizeof(int);
    int* offsets = (int*)w;    w += (NNODES + 1) * sizeof(int);
    int* cursor  = (int*)w;    w += NNODES * sizeof(int);
    int* esrc    = (int*)w;    w += NEDGES * sizeof(int);

    // ---- CSR build (once; shared by all 3 layers) ----
    zero_kernel<<<64, 256, 0, stream>>>((float*)counts, NNODES);
    count_kernel<<<(NEDGES + 255) / 256, 256, 0, stream>>>(e_dst, counts, NEDGES);
    scan_kernel<<<1, 1024, 0, stream>>>(counts, offsets, NNODES);
    copy_int_kernel<<<(NNODES + 255) / 256, 256, 0, stream>>>(offsets, cursor, NNODES);
    scatter_kernel<<<(NEDGES + 255) / 256, 256, 0, stream>>>(e_src, e_dst, cursor, esrc, NEDGES);

    // ---- bf16 conversions (x and transposed weights) ----
    {
        int nx = NNODES * INF_;
        conv_bf16_kernel<<<(nx + 255) / 256, 256, 0, stream>>>(x, x_bf, nx);
        int n1 = INF_ * HC_;
        transconv_kernel<<<(n1 + 255) / 256, 256, 0, stream>>>(W1, Wt1, INF_, HC_);
        int n2 = HC_ * HC_;
        transconv_kernel<<<(n2 + 255) / 256, 256, 0, stream>>>(W2, Wt2, HC_, HC_);
        int n3 = HC_ * OUTF_;
        transconv_kernel<<<(n3 + 255) / 256, 256, 0, stream>>>(W3, Wt3, HC_, OUTF_);
    }

    dim3 gb(256);
    dim3 gg1((HC_ + 63) / 64, (NNODES + 63) / 64);

    // ---- Layer 1 ----
    gemm_bf16_kernel<<<gg1, gb, 0, stream>>>(x_bf, Wt1, nullptr, (ushort_t*)xpb, NNODES, INF_, HC_);
    logits_bf16_kernel<<<NNODES, 256, 0, stream>>>(xpb, a_src1, a_dst1, s_log, d_log, HEADS_, HID_, HID_ / 2);
    aggregate_bf16_kernel<<<NNODES, 256, 0, stream>>>(xpb, s_log, d_log, offsets, esrc, b1, hbuf, HEADS_, HID_, HID_ / 2);
    zero_kernel<<<4, 256, 0, stream>>>(bns, 2 * HC_);
    bn_stats_kernel<<<64, 512, 0, stream>>>(hbuf, bns, bnss, NNODES, HC_);
    bn_finalize_kernel<<<1, 512, 0, stream>>>(bns, bnss, g1, be1, bnscale, bnshift, NNODES, HC_);
    bn_apply_elu_bf16_kernel<<<(NNODES * 256 + 255) / 256, 256, 0, stream>>>(hbuf, bnscale, bnshift, hbf, NNODES * 256);

    // ---- Layer 2 ----
    gemm_bf16_kernel<<<gg1, gb, 0, stream>>>((const ushort_t*)hbf, Wt2, nullptr, (ushort_t*)xpb, NNODES, HC_, HC_);
    logits_bf16_kernel<<<NNODES, 256, 0, stream>>>(xpb, a_src2, a_dst2, s_log, d_log, HEADS_, HID_, HID_ / 2);
    aggregate_bf16_kernel<<<NNODES, 256, 0, stream>>>(xpb, s_log, d_log, offsets, esrc, b2, hbuf, HEADS_, HID_, HID_ / 2);
    zero_kernel<<<4, 256, 0, stream>>>(bns, 2 * HC_);
    bn_stats_kernel<<<64, 512, 0, stream>>>(hbuf, bns, bnss, NNODES, HC_);
    bn_finalize_kernel<<<1, 512, 0, stream>>>(bns, bnss, g2, be2, bnscale, bnshift, NNODES, HC_);
    bn_apply_elu_bf16_kernel<<<(NNODES * 256 + 255) / 256, 256, 0, stream>>>(hbuf, bnscale, bnshift, hbf, NNODES * 256);

    // ---- Layer 3 (H=1, C=500, output straight to d_out) ----
    dim3 gg3((OUTF_ + 63) / 64, (NNODES + 63) / 64);
    gemm_bf16_kernel<<<gg3, gb, 0, stream>>>((const ushort_t*)hbf, Wt3, nullptr, (ushort_t*)xpb, NNODES, HC_, OUTF_);
    logits_bf16_kernel<<<NNODES, 256, 0, stream>>>(xpb, a_src3, a_dst3, s_log, d_log, 1, OUTF_, OUTF_ / 2);
    aggregate_bf16_kernel<<<NNODES, 256, 0, stream>>>(xpb, s_log, d_log, offsets, esrc, b3, out, 1, OUTF_, OUTF_ / 2);
}

// Round 3
// 598.689 us; speedup vs baseline: 1.8826x; 1.1227x over previous
//
#include <hip/hip_runtime.h>
#include <hip/hip_bf16.h>

// Problem constants (from reference)
#define NNODES 10000
#define NEDGES 320000
#define INF_   1280
#define HID_   128
#define HEADS_ 4
#define OUTF_  500
#define HC_    512          // HEADS_*HID_
#define NEG_SLOPE 0.2f
#define BN_EPS 1e-5f

typedef __attribute__((ext_vector_type(8))) short short8x;
typedef __attribute__((ext_vector_type(4))) float f32x4;
typedef unsigned short ushort_t;
typedef unsigned int uint_t;

__device__ __forceinline__ ushort_t f2bf(float f) {
    uint_t u = __float_as_uint(f);
    u = (u + 0x7fffu + ((u >> 16) & 1u)) >> 16;   // round-to-nearest-even
    return (ushort_t)u;
}
__device__ __forceinline__ float bf_lo(uint_t p) { return __uint_as_float(p << 16); }
__device__ __forceinline__ float bf_hi(uint_t p) { return __uint_as_float(p & 0xffff0000u); }
__device__ __forceinline__ float lrelu(float x) { return (x >= 0.f) ? x : NEG_SLOPE * x; }

// ---------------------------------------------------------------------------
// utility kernels
// ---------------------------------------------------------------------------
__global__ void zero_kernel(float* __restrict__ p, size_t n) {
    size_t i = (size_t)blockIdx.x * blockDim.x + threadIdx.x;
    size_t stride = (size_t)gridDim.x * blockDim.x;
    for (; i < n; i += stride) p[i] = 0.0f;
}

__global__ void copy_int_kernel(const int* __restrict__ src, int* __restrict__ dst, int n) {
    int i = blockIdx.x * blockDim.x + threadIdx.x;
    if (i < n) dst[i] = src[i];
}

// fp32 -> bf16 (flat)
__global__ void conv_bf16_kernel(const float* __restrict__ in, ushort_t* __restrict__ out, int n) {
    int i = blockIdx.x * blockDim.x + threadIdx.x;
    if (i < n) out[i] = f2bf(in[i]);
}

// fp32 W[K][N] -> bf16 Wt[N][K]  (write-coalesced)
__global__ void transconv_kernel(const float* __restrict__ W, ushort_t* __restrict__ Wt, int K, int N) {
    int i = blockIdx.x * blockDim.x + threadIdx.x;
    if (i < N * K) {
        int n = i / K;
        int k = i - n * K;
        Wt[i] = f2bf(W[(size_t)k * N + n]);
    }
}

// ---------------------------------------------------------------------------
// CSR build (by destination) — edges are identical across layers, built once
// ---------------------------------------------------------------------------
__global__ void count_kernel(const int* __restrict__ dst, int* __restrict__ counts, int E) {
    int e = blockIdx.x * blockDim.x + threadIdx.x;
    if (e < E) atomicAdd(&counts[dst[e]], 1);
}

__global__ void scan_kernel(const int* __restrict__ counts, int* __restrict__ offsets, int n) {
    __shared__ int tmp[1024];
    int tid = threadIdx.x;
    int carry = 0;
    int nchunk = (n + 1023) / 1024;
    for (int ch = 0; ch < nchunk; ++ch) {
        int i = ch * 1024 + tid;
        int v = (i < n) ? counts[i] : 0;
        tmp[tid] = v;
        __syncthreads();
        for (int off = 1; off < 1024; off <<= 1) {
            int t = (tid >= off) ? tmp[tid - off] : 0;
            __syncthreads();
            tmp[tid] += t;
            __syncthreads();
        }
        if (i < n) offsets[i] = carry + tmp[tid] - v;  // exclusive scan
        carry += tmp[1023];
        __syncthreads();
    }
    if (tid == 0) offsets[n] = carry;
}

__global__ void scatter_kernel(const int* __restrict__ src, const int* __restrict__ dst,
                               int* __restrict__ cursor, int* __restrict__ esrc, int E) {
    int e = blockIdx.x * blockDim.x + threadIdx.x;
    if (e < E) {
        int p = atomicAdd(&cursor[dst[e]], 1);
        esrc[p] = src[e];
    }
}

// ---------------------------------------------------------------------------
// bf16 MFMA GEMM: C[M,N] = A[M,K] @ B[K,N]
//   A row-major bf16 [M][K]; B given pre-transposed: Wt[N][K] bf16.
//   64x64 tile, BK=32, 256 threads = 4 waves, each wave a 32x32 quadrant
//   (2x2 grid of 16x16x32 MFMAs). K must be a multiple of 32.
// ---------------------------------------------------------------------------
#define LDT 40   // LDS row stride in bf16 units (padded; 80B keeps 16B align)

__global__ __launch_bounds__(256) void gemm_bf16_kernel(
    const ushort_t* __restrict__ A,    // [M][K] bf16
    const ushort_t* __restrict__ Bt,   // [N][K] bf16 (transposed weights)
    float* __restrict__ Cf,            // [M][N] fp32 or nullptr
    ushort_t* __restrict__ Cb,         // [M][N] bf16 or nullptr
    int M, int K, int N)
{
    __shared__ __align__(16) ushort_t As[64 * LDT];
    __shared__ __align__(16) ushort_t Bs[64 * LDT];

    int tid  = threadIdx.x;
    int lane = tid & 63;
    int w    = tid >> 6;
    int wm   = (w & 1) * 32;
    int wn   = (w >> 1) * 32;
    int quad = lane >> 4;
    int c16  = lane & 15;
    int m0 = blockIdx.y * 64;
    int n0 = blockIdx.x * 64;

    f32x4 acc[2][2];
#pragma unroll
    for (int i = 0; i < 2; ++i)
#pragma unroll
        for (int j = 0; j < 2; ++j)
#pragma unroll
            for (int r = 0; r < 4; ++r) acc[i][j][r] = 0.0f;

    int sr = tid >> 2;          // 0..63 row within tile
    int sk = (tid & 3) * 8;     // k chunk: 0,8,16,24

    for (int k0 = 0; k0 < K; k0 += 32) {
        uint4 av = make_uint4(0, 0, 0, 0);
        int gm = m0 + sr;
        if (gm < M) av = *(const uint4*)(A + (size_t)gm * K + k0 + sk);
        *(uint4*)&As[sr * LDT + sk] = av;

        uint4 bv = make_uint4(0, 0, 0, 0);
        int gn = n0 + sr;
        if (gn < N) bv = *(const uint4*)(Bt + (size_t)gn * K + k0 + sk);
        *(uint4*)&Bs[sr * LDT + sk] = bv;
        __syncthreads();

        short8x af0 = *(const short8x*)&As[(wm +      c16) * LDT + quad * 8];
        short8x af1 = *(const short8x*)&As[(wm + 16 + c16) * LDT + quad * 8];
        short8x bf0 = *(const short8x*)&Bs[(wn +      c16) * LDT + quad * 8];
        short8x bf1 = *(const short8x*)&Bs[(wn + 16 + c16) * LDT + quad * 8];

        acc[0][0] = __builtin_amdgcn_mfma_f32_16x16x32_bf16(af0, bf0, acc[0][0], 0, 0, 0);
        acc[0][1] = __builtin_amdgcn_mfma_f32_16x16x32_bf16(af0, bf1, acc[0][1], 0, 0, 0);
        acc[1][0] = __builtin_amdgcn_mfma_f32_16x16x32_bf16(af1, bf0, acc[1][0], 0, 0, 0);
        acc[1][1] = __builtin_amdgcn_mfma_f32_16x16x32_bf16(af1, bf1, acc[1][1], 0, 0, 0);
        __syncthreads();
    }

#pragma unroll
    for (int mt = 0; mt < 2; ++mt) {
#pragma unroll
        for (int nt = 0; nt < 2; ++nt) {
#pragma unroll
            for (int r = 0; r < 4; ++r) {
                int row = m0 + wm + mt * 16 + quad * 4 + r;
                int col = n0 + wn + nt * 16 + c16;
                if (row < M && col < N) {
                    float v = acc[mt][nt][r];
                    if (Cf) Cf[(size_t)row * N + col] = v;
                    if (Cb) Cb[(size_t)row * N + col] = f2bf(v);
                }
            }
        }
    }
}

// ---------------------------------------------------------------------------
// attention logits from bf16 xp (packed pairs). block=256; group G=256/H.
// ---------------------------------------------------------------------------
__global__ __launch_bounds__(256) void logits_bf16_kernel(
    const uint_t* __restrict__ xpb,     // [node][HCp] packed 2xbf16
    const float* __restrict__ a_src, const float* __restrict__ a_dst,
    float* __restrict__ s, float* __restrict__ d,
    int H, int C, int Cpair)
{
    int node = blockIdx.x;
    int tid = threadIdx.x;
    int G = 256 / H;
    int h = tid / G;
    int cp = tid - h * G;
    int HCp = H * Cpair;
    float vs = 0.f, vd = 0.f;
    if (cp < Cpair) {
        uint_t p = xpb[(size_t)node * HCp + h * Cpair + cp];
        float f0 = bf_lo(p), f1 = bf_hi(p);
        int c = cp * 2;
        vs = f0 * a_src[h * C + c] + f1 * a_src[h * C + c + 1];
        vd = f0 * a_dst[h * C + c] + f1 * a_dst[h * C + c + 1];
    }
    __shared__ float rs[256];
    __shared__ float rd[256];
    rs[tid] = vs; rd[tid] = vd;
    __syncthreads();
    for (int off = G >> 1; off > 0; off >>= 1) {
        if (cp < off) { rs[tid] += rs[tid + off]; rd[tid] += rd[tid + off]; }
        __syncthreads();
    }
    if (cp == 0) { s[node * H + h] = rs[tid]; d[node * H + h] = rd[tid]; }
}

// ---------------------------------------------------------------------------
// scalar softmax over each dst's edge list: one wave per dst node.
// Pass 1: per-head max (incl. self-loop); pass 2: w=exp(e-m) stored to ew,
// summed -> zinv. Self-loop weight stored separately.
// ---------------------------------------------------------------------------
template<int H>
__global__ __launch_bounds__(64) void edge_softmax_kernel(
    const float* __restrict__ s,     // [node][H]
    const float* __restrict__ dlog,  // [node][H]
    const int* __restrict__ offsets, const int* __restrict__ esrc,
    float* __restrict__ ew,          // [E][H] unnormalized exp weights
    float* __restrict__ wself,       // [node][H]
    float* __restrict__ zinv)        // [node][H]
{
    int dst = blockIdx.x;
    int lane = threadIdx.x;
    int e0 = offsets[dst], e1 = offsets[dst + 1];

    float dh[H], selfe[H], mh[H], zh[H];
#pragma unroll
    for (int h = 0; h < H; ++h) {
        dh[h] = dlog[dst * H + h];
        selfe[h] = lrelu(s[dst * H + h] + dh[h]);
        mh[h] = selfe[h];
        zh[h] = 0.f;
    }

    // pass 1: max
    for (int j = e0 + lane; j < e1; j += 64) {
        int src = esrc[j];
        if (H == 4) {
            float4 sv = ((const float4*)s)[src];
            mh[0] = fmaxf(mh[0], lrelu(sv.x + dh[0]));
            mh[1] = fmaxf(mh[1], lrelu(sv.y + dh[1]));
            mh[2] = fmaxf(mh[2], lrelu(sv.z + dh[2]));
            mh[3] = fmaxf(mh[3], lrelu(sv.w + dh[3]));
        } else {
#pragma unroll
            for (int h = 0; h < H; ++h)
                mh[h] = fmaxf(mh[h], lrelu(s[src * H + h] + dh[h]));
        }
    }
#pragma unroll
    for (int h = 0; h < H; ++h)
        for (int off = 32; off > 0; off >>= 1)
            mh[h] = fmaxf(mh[h], __shfl_xor(mh[h], off));

    // pass 2: w = exp(e - m), store, sum
    for (int j = e0 + lane; j < e1; j += 64) {
        int src = esrc[j];
        if (H == 4) {
            float4 sv = ((const float4*)s)[src];
            float w0 = __expf(lrelu(sv.x + dh[0]) - mh[0]);
            float w1 = __expf(lrelu(sv.y + dh[1]) - mh[1]);
            float w2 = __expf(lrelu(sv.z + dh[2]) - mh[2]);
            float w3 = __expf(lrelu(sv.w + dh[3]) - mh[3]);
            ((float4*)ew)[j] = make_float4(w0, w1, w2, w3);
            zh[0] += w0; zh[1] += w1; zh[2] += w2; zh[3] += w3;
        } else {
#pragma unroll
            for (int h = 0; h < H; ++h) {
                float w = __expf(lrelu(s[src * H + h] + dh[h]) - mh[h]);
                ew[(size_t)j * H + h] = w;
                zh[h] += w;
            }
        }
    }
#pragma unroll
    for (int h = 0; h < H; ++h)
        for (int off = 32; off > 0; off >>= 1)
            zh[h] += __shfl_xor(zh[h], off);

    if (lane == 0) {
#pragma unroll
        for (int h = 0; h < H; ++h) {
            float ws = __expf(selfe[h] - mh[h]);
            wself[dst * H + h] = ws;
            zinv[dst * H + h] = 1.0f / (zh[h] + ws);
        }
    }
}

// ---------------------------------------------------------------------------
// weighted gather-aggregate: out[dst] = (wself*xp[dst] + sum_j w_j*xp[src_j])
//                                       * zinv + bias
// one block of 256 per dst; thread = (head, channel-pair). pure FMA loop.
// ---------------------------------------------------------------------------
template<int H>
__global__ __launch_bounds__(256) void aggregate2_kernel(
    const uint_t* __restrict__ xpb,     // [node][HCp] packed 2xbf16
    const int* __restrict__ offsets, const int* __restrict__ esrc,
    const float* __restrict__ ew,       // [E][H]
    const float* __restrict__ wself,    // [node][H]
    const float* __restrict__ zinv,     // [node][H]
    const float* __restrict__ bias,
    float* __restrict__ out,
    int C, int Cpair)
{
    int dst = blockIdx.x;
    int tid = threadIdx.x;
    int HCp = H * Cpair;
    if (tid >= HCp) return;   // no __syncthreads below
    int h = tid / Cpair;
    int cp = tid - h * Cpair;

    float ws = wself[dst * H + h];
    uint_t p = xpb[(size_t)dst * HCp + tid];
    float acc0 = ws * bf_lo(p);
    float acc1 = ws * bf_hi(p);

    int e0 = offsets[dst], e1 = offsets[dst + 1];
    int j = e0;
    for (; j + 1 < e1; j += 2) {
        int s0 = esrc[j], s1 = esrc[j + 1];
        float w0 = ew[(size_t)j * H + h];
        float w1 = ew[(size_t)(j + 1) * H + h];
        uint_t q0 = xpb[(size_t)s0 * HCp + tid];
        uint_t q1 = xpb[(size_t)s1 * HCp + tid];
        acc0 += w0 * bf_lo(q0) + w1 * bf_lo(q1);
        acc1 += w0 * bf_hi(q0) + w1 * bf_hi(q1);
    }
    if (j < e1) {
        int s0 = esrc[j];
        float w0 = ew[(size_t)j * H + h];
        uint_t q0 = xpb[(size_t)s0 * HCp + tid];
        acc0 += w0 * bf_lo(q0);
        acc1 += w0 * bf_hi(q0);
    }

    float zi = zinv[dst * H + h];
    int c = cp * 2;
    size_t base = (size_t)dst * (H * C) + h * C + c;
    out[base]     = acc0 * zi + bias[h * C + c];
    out[base + 1] = acc1 * zi + bias[h * C + c + 1];
}

// ---------------------------------------------------------------------------
// BatchNorm (training-mode normalization, biased var) + ELU -> bf16
// ---------------------------------------------------------------------------
__global__ __launch_bounds__(512) void bn_stats_kernel(const float* __restrict__ h,
                                                       float* __restrict__ sums,
                                                       float* __restrict__ sumsq,
                                                       int Nrows, int Ncols) {
    int c = threadIdx.x;  // Ncols == 512 == blockDim
    float sm = 0.f, sq = 0.f;
    for (int r = blockIdx.x; r < Nrows; r += gridDim.x) {
        float v = h[(size_t)r * Ncols + c];
        sm += v;
        sq += v * v;
    }
    atomicAdd(&sums[c], sm);
    atomicAdd(&sumsq[c], sq);
}

__global__ __launch_bounds__(512) void bn_finalize_kernel(const float* __restrict__ sums,
                                                          const float* __restrict__ sumsq,
                                                          const float* __restrict__ gamma,
                                                          const float* __restrict__ beta,
                                                          float* __restrict__ scale,
                                                          float* __restrict__ shift,
                                                          int Nrows, int Ncols) {
    int c = threadIdx.x;
    if (c < Ncols) {
        float mu = sums[c] / (float)Nrows;
        float var = sumsq[c] / (float)Nrows - mu * mu;
        float sc = gamma[c] * rsqrtf(var + BN_EPS);
        scale[c] = sc;
        shift[c] = beta[c] - mu * sc;
    }
}

// h fp32 [N][512] -> hbf packed bf16 pairs [N][256]
__global__ void bn_apply_elu_bf16_kernel(const float* __restrict__ h,
                                         const float* __restrict__ scale,
                                         const float* __restrict__ shift,
                                         uint_t* __restrict__ hbf,
                                         int npairs) {
    int i = blockIdx.x * blockDim.x + threadIdx.x;
    if (i < npairs) {
        int c0 = (i & 255) * 2;   // Ncols = 512
        float2 hv = ((const float2*)h)[i];
        float v0 = hv.x * scale[c0]     + shift[c0];
        float v1 = hv.y * scale[c0 + 1] + shift[c0 + 1];
        v0 = (v0 > 0.f) ? v0 : (__expf(v0) - 1.0f);
        v1 = (v1 > 0.f) ? v1 : (__expf(v1) - 1.0f);
        hbf[i] = ((uint_t)f2bf(v1) << 16) | (uint_t)f2bf(v0);
    }
}

// ---------------------------------------------------------------------------
// launch
// ---------------------------------------------------------------------------
extern "C" void kernel_launch(void* const* d_in, const int* in_sizes, int n_in,
                              void* d_out, int out_size, void* d_ws, size_t ws_size,
                              hipStream_t stream) {
    const float* x      = (const float*)d_in[0];
    const int*   ei     = (const int*)d_in[1];
    const float* W1     = (const float*)d_in[2];
    const float* a_src1 = (const float*)d_in[3];
    const float* a_dst1 = (const float*)d_in[4];
    const float* b1     = (const float*)d_in[5];
    const float* g1     = (const float*)d_in[6];
    const float* be1    = (const float*)d_in[7];
    const float* W2     = (const float*)d_in[8];
    const float* a_src2 = (const float*)d_in[9];
    const float* a_dst2 = (const float*)d_in[10];
    const float* b2     = (const float*)d_in[11];
    const float* g2     = (const float*)d_in[12];
    const float* be2    = (const float*)d_in[13];
    const float* W3     = (const float*)d_in[14];
    const float* a_src3 = (const float*)d_in[15];
    const float* a_dst3 = (const float*)d_in[16];
    const float* b3     = (const float*)d_in[17];
    float* out = (float*)d_out;

    const int* e_src = ei;           // edge_index[0]
    const int* e_dst = ei + NEDGES;  // edge_index[1]

    // ---- workspace layout ----
    char* w = (char*)d_ws;
    // region 0: x_bf (25.6 MB), later reused as hbuf fp32 (20.48 MB) + ew (5.12 MB)
    ushort_t* x_bf = (ushort_t*)w;
    float*    hbuf = (float*)w;                               // alias after L1 GEMM
    float*    ew   = (float*)(w + (size_t)NNODES * HC_ * sizeof(float));  // tail 5.12 MB
    w += (size_t)NNODES * INF_ * sizeof(ushort_t);            // 25,600,000
    uint_t* xpb = (uint_t*)w;  w += (size_t)NNODES * HC_ * sizeof(ushort_t);   // 10,240,000
    uint_t* hbf = (uint_t*)w;  w += (size_t)NNODES * HC_ * sizeof(ushort_t);   // 10,240,000
    ushort_t* Wt1 = (ushort_t*)w; w += (size_t)INF_ * HC_ * sizeof(ushort_t);  // 1,310,720
    ushort_t* Wt2 = (ushort_t*)w; w += (size_t)HC_ * HC_ * sizeof(ushort_t);   //   524,288
    ushort_t* Wt3 = (ushort_t*)w; w += (size_t)HC_ * OUTF_ * sizeof(ushort_t); //   512,000
    float* s_log = (float*)w;  w += NNODES * HEADS_ * sizeof(float);
    float* d_log = (float*)w;  w += NNODES * HEADS_ * sizeof(float);
    float* wself = (float*)w;  w += NNODES * HEADS_ * sizeof(float);
    float* zinv  = (float*)w;  w += NNODES * HEADS_ * sizeof(float);
    float* bns   = (float*)w;  w += HC_ * sizeof(float);
    float* bnss  = (float*)w;  w += HC_ * sizeof(float);
    float* bnscale = (float*)w; w += HC_ * sizeof(float);
    float* bnshift = (float*)w; w += HC_ * sizeof(float);
    int* counts  = (int*)w;    w += NNODES * sizeof(int);
    int* offsets = (int*)w;    w += (NNODES + 1) * sizeof(int);
    int* cursor  = (int*)w;    w += NNODES * sizeof(int);
    int* esrc    = (int*)w;    w += NEDGES * sizeof(int);

    // ---- CSR build (once; shared by all 3 layers) ----
    zero_kernel<<<64, 256, 0, stream>>>((float*)counts, NNODES);
    count_kernel<<<(NEDGES + 255) / 256, 256, 0, stream>>>(e_dst, counts, NEDGES);
    scan_kernel<<<1, 1024, 0, stream>>>(counts, offsets, NNODES);
    copy_int_kernel<<<(NNODES + 255) / 256, 256, 0, stream>>>(offsets, cursor, NNODES);
    scatter_kernel<<<(NEDGES + 255) / 256, 256, 0, stream>>>(e_src, e_dst, cursor, esrc, NEDGES);

    // ---- bf16 conversions (x and transposed weights) ----
    {
        int nx = NNODES * INF_;
        conv_bf16_kernel<<<(nx + 255) / 256, 256, 0, stream>>>(x, x_bf, nx);
        int n1 = INF_ * HC_;
        transconv_kernel<<<(n1 + 255) / 256, 256, 0, stream>>>(W1, Wt1, INF_, HC_);
        int n2 = HC_ * HC_;
        transconv_kernel<<<(n2 + 255) / 256, 256, 0, stream>>>(W2, Wt2, HC_, HC_);
        int n3 = HC_ * OUTF_;
        transconv_kernel<<<(n3 + 255) / 256, 256, 0, stream>>>(W3, Wt3, HC_, OUTF_);
    }

    dim3 gb(256);
    dim3 gg1((HC_ + 63) / 64, (NNODES + 63) / 64);

    // ---- Layer 1 ----   (x_bf dead after this GEMM; hbuf/ew alias its region)
    gemm_bf16_kernel<<<gg1, gb, 0, stream>>>(x_bf, Wt1, nullptr, (ushort_t*)xpb, NNODES, INF_, HC_);
    logits_bf16_kernel<<<NNODES, 256, 0, stream>>>(xpb, a_src1, a_dst1, s_log, d_log, HEADS_, HID_, HID_ / 2);
    edge_softmax_kernel<HEADS_><<<NNODES, 64, 0, stream>>>(s_log, d_log, offsets, esrc, ew, wself, zinv);
    aggregate2_kernel<HEADS_><<<NNODES, 256, 0, stream>>>(xpb, offsets, esrc, ew, wself, zinv, b1, hbuf, HID_, HID_ / 2);
    zero_kernel<<<4, 256, 0, stream>>>(bns, 2 * HC_);
    bn_stats_kernel<<<64, 512, 0, stream>>>(hbuf, bns, bnss, NNODES, HC_);
    bn_finalize_kernel<<<1, 512, 0, stream>>>(bns, bnss, g1, be1, bnscale, bnshift, NNODES, HC_);
    bn_apply_elu_bf16_kernel<<<(NNODES * 256 + 255) / 256, 256, 0, stream>>>(hbuf, bnscale, bnshift, hbf, NNODES * 256);

    // ---- Layer 2 ----
    gemm_bf16_kernel<<<gg1, gb, 0, stream>>>((const ushort_t*)hbf, Wt2, nullptr, (ushort_t*)xpb, NNODES, HC_, HC_);
    logits_bf16_kernel<<<NNODES, 256, 0, stream>>>(xpb, a_src2, a_dst2, s_log, d_log, HEADS_, HID_, HID_ / 2);
    edge_softmax_kernel<HEADS_><<<NNODES, 64, 0, stream>>>(s_log, d_log, offsets, esrc, ew, wself, zinv);
    aggregate2_kernel<HEADS_><<<NNODES, 256, 0, stream>>>(xpb, offsets, esrc, ew, wself, zinv, b2, hbuf, HID_, HID_ / 2);
    zero_kernel<<<4, 256, 0, stream>>>(bns, 2 * HC_);
    bn_stats_kernel<<<64, 512, 0, stream>>>(hbuf, bns, bnss, NNODES, HC_);
    bn_finalize_kernel<<<1, 512, 0, stream>>>(bns, bnss, g2, be2, bnscale, bnshift, NNODES, HC_);
    bn_apply_elu_bf16_kernel<<<(NNODES * 256 + 255) / 256, 256, 0, stream>>>(hbuf, bnscale, bnshift, hbf, NNODES * 256);

    // ---- Layer 3 (H=1, C=500, output straight to d_out) ----
    dim3 gg3((OUTF_ + 63) / 64, (NNODES + 63) / 64);
    gemm_bf16_kernel<<<gg3, gb, 0, stream>>>((const ushort_t*)hbf, Wt3, nullptr, (ushort_t*)xpb, NNODES, HC_, OUTF_);
    logits_bf16_kernel<<<NNODES, 256, 0, stream>>>(xpb, a_src3, a_dst3, s_log, d_log, 1, OUTF_, OUTF_ / 2);
    edge_softmax_kernel<1><<<NNODES, 64, 0, stream>>>(s_log, d_log, offsets, esrc, ew, wself, zinv);
    aggregate2_kernel<1><<<NNODES, 256, 0, stream>>>(xpb, offsets, esrc, ew, wself, zinv, b3, out, OUTF_, OUTF_ / 2);
}

// Round 4
// 568.429 us; speedup vs baseline: 1.9828x; 1.0532x over previous
//
#include <hip/hip_runtime.h>
#include <hip/hip_bf16.h>

// Problem constants (from reference)
#define NNODES 10000
#define NEDGES 320000
#define INF_   1280
#define HID_   128
#define HEADS_ 4
#define OUTF_  500
#define HC_    512          // HEADS_*HID_
#define NEG_SLOPE 0.2f
#define BN_EPS 1e-5f

typedef __attribute__((ext_vector_type(8))) short short8x;
typedef __attribute__((ext_vector_type(4))) float f32x4;
typedef unsigned short ushort_t;
typedef unsigned int uint_t;

__device__ __forceinline__ ushort_t f2bf(float f) {
    uint_t u = __float_as_uint(f);
    u = (u + 0x7fffu + ((u >> 16) & 1u)) >> 16;   // round-to-nearest-even
    return (ushort_t)u;
}
__device__ __forceinline__ float bf_lo(uint_t p) { return __uint_as_float(p << 16); }
__device__ __forceinline__ float bf_hi(uint_t p) { return __uint_as_float(p & 0xffff0000u); }
__device__ __forceinline__ float lrelu(float x) { return (x >= 0.f) ? x : NEG_SLOPE * x; }

// ---------------------------------------------------------------------------
// utility kernels
// ---------------------------------------------------------------------------
__global__ void zero_kernel(float* __restrict__ p, size_t n) {
    size_t i = (size_t)blockIdx.x * blockDim.x + threadIdx.x;
    size_t stride = (size_t)gridDim.x * blockDim.x;
    for (; i < n; i += stride) p[i] = 0.0f;
}

__global__ void copy_int_kernel(const int* __restrict__ src, int* __restrict__ dst, int n) {
    int i = blockIdx.x * blockDim.x + threadIdx.x;
    if (i < n) dst[i] = src[i];
}

// fp32 -> bf16 (flat)
__global__ void conv_bf16_kernel(const float* __restrict__ in, ushort_t* __restrict__ out, int n) {
    int i = blockIdx.x * blockDim.x + threadIdx.x;
    if (i < n) out[i] = f2bf(in[i]);
}

// fp32 W[K][N] -> bf16 Wt[N][K]  (write-coalesced)
__global__ void transconv_kernel(const float* __restrict__ W, ushort_t* __restrict__ Wt, int K, int N) {
    int i = blockIdx.x * blockDim.x + threadIdx.x;
    if (i < N * K) {
        int n = i / K;
        int k = i - n * K;
        Wt[i] = f2bf(W[(size_t)k * N + n]);
    }
}

// ---------------------------------------------------------------------------
// CSR build (by destination) — edges are identical across layers, built once
// ---------------------------------------------------------------------------
__global__ void count_kernel(const int* __restrict__ dst, int* __restrict__ counts, int E) {
    int e = blockIdx.x * blockDim.x + threadIdx.x;
    if (e < E) atomicAdd(&counts[dst[e]], 1);
}

__global__ void scan_kernel(const int* __restrict__ counts, int* __restrict__ offsets, int n) {
    __shared__ int tmp[1024];
    int tid = threadIdx.x;
    int carry = 0;
    int nchunk = (n + 1023) / 1024;
    for (int ch = 0; ch < nchunk; ++ch) {
        int i = ch * 1024 + tid;
        int v = (i < n) ? counts[i] : 0;
        tmp[tid] = v;
        __syncthreads();
        for (int off = 1; off < 1024; off <<= 1) {
            int t = (tid >= off) ? tmp[tid - off] : 0;
            __syncthreads();
            tmp[tid] += t;
            __syncthreads();
        }
        if (i < n) offsets[i] = carry + tmp[tid] - v;  // exclusive scan
        carry += tmp[1023];
        __syncthreads();
    }
    if (tid == 0) offsets[n] = carry;
}

__global__ void scatter_kernel(const int* __restrict__ src, const int* __restrict__ dst,
                               int* __restrict__ cursor, int* __restrict__ esrc, int E) {
    int e = blockIdx.x * blockDim.x + threadIdx.x;
    if (e < E) {
        int p = atomicAdd(&cursor[dst[e]], 1);
        esrc[p] = src[e];
    }
}

// ---------------------------------------------------------------------------
// bf16 MFMA GEMM: C[M,N] = A[M,K] @ B[K,N], C row stride = ldc (>= N).
//   Pad columns [N, ldc) are written as zero.
//   A row-major bf16 [M][K]; B pre-transposed: Wt[N][K] bf16.
//   64x64 tile, BK=32, 256 threads = 4 waves, each wave a 32x32 quadrant.
// ---------------------------------------------------------------------------
#define LDT 40   // LDS row stride in bf16 units (padded; 80B keeps 16B align)

__global__ __launch_bounds__(256) void gemm_bf16_kernel(
    const ushort_t* __restrict__ A,    // [M][K] bf16
    const ushort_t* __restrict__ Bt,   // [N][K] bf16 (transposed weights)
    float* __restrict__ Cf,            // [M][ldc] fp32 or nullptr
    ushort_t* __restrict__ Cb,         // [M][ldc] bf16 or nullptr
    int M, int K, int N, int ldc)
{
    __shared__ __align__(16) ushort_t As[64 * LDT];
    __shared__ __align__(16) ushort_t Bs[64 * LDT];

    int tid  = threadIdx.x;
    int lane = tid & 63;
    int w    = tid >> 6;
    int wm   = (w & 1) * 32;
    int wn   = (w >> 1) * 32;
    int quad = lane >> 4;
    int c16  = lane & 15;
    int m0 = blockIdx.y * 64;
    int n0 = blockIdx.x * 64;

    f32x4 acc[2][2];
#pragma unroll
    for (int i = 0; i < 2; ++i)
#pragma unroll
        for (int j = 0; j < 2; ++j)
#pragma unroll
            for (int r = 0; r < 4; ++r) acc[i][j][r] = 0.0f;

    int sr = tid >> 2;          // 0..63 row within tile
    int sk = (tid & 3) * 8;     // k chunk: 0,8,16,24

    for (int k0 = 0; k0 < K; k0 += 32) {
        uint4 av = make_uint4(0, 0, 0, 0);
        int gm = m0 + sr;
        if (gm < M) av = *(const uint4*)(A + (size_t)gm * K + k0 + sk);
        *(uint4*)&As[sr * LDT + sk] = av;

        uint4 bv = make_uint4(0, 0, 0, 0);
        int gn = n0 + sr;
        if (gn < N) bv = *(const uint4*)(Bt + (size_t)gn * K + k0 + sk);
        *(uint4*)&Bs[sr * LDT + sk] = bv;
        __syncthreads();

        short8x af0 = *(const short8x*)&As[(wm +      c16) * LDT + quad * 8];
        short8x af1 = *(const short8x*)&As[(wm + 16 + c16) * LDT + quad * 8];
        short8x bf0 = *(const short8x*)&Bs[(wn +      c16) * LDT + quad * 8];
        short8x bf1 = *(const short8x*)&Bs[(wn + 16 + c16) * LDT + quad * 8];

        acc[0][0] = __builtin_amdgcn_mfma_f32_16x16x32_bf16(af0, bf0, acc[0][0], 0, 0, 0);
        acc[0][1] = __builtin_amdgcn_mfma_f32_16x16x32_bf16(af0, bf1, acc[0][1], 0, 0, 0);
        acc[1][0] = __builtin_amdgcn_mfma_f32_16x16x32_bf16(af1, bf0, acc[1][0], 0, 0, 0);
        acc[1][1] = __builtin_amdgcn_mfma_f32_16x16x32_bf16(af1, bf1, acc[1][1], 0, 0, 0);
        __syncthreads();
    }

#pragma unroll
    for (int mt = 0; mt < 2; ++mt) {
#pragma unroll
        for (int nt = 0; nt < 2; ++nt) {
#pragma unroll
            for (int r = 0; r < 4; ++r) {
                int row = m0 + wm + mt * 16 + quad * 4 + r;
                int col = n0 + wn + nt * 16 + c16;
                if (row < M && col < ldc) {
                    float v = (col < N) ? acc[mt][nt][r] : 0.0f;
                    if (Cf) Cf[(size_t)row * ldc + col] = v;
                    if (Cb) Cb[(size_t)row * ldc + col] = f2bf(v);
                }
            }
        }
    }
}

// ---------------------------------------------------------------------------
// attention logits from bf16 xp (packed pairs, row stride ldp uints).
// block=256; group G=256/H.
// ---------------------------------------------------------------------------
__global__ __launch_bounds__(256) void logits_bf16_kernel(
    const uint_t* __restrict__ xpb,     // [node][ldp] packed 2xbf16
    const float* __restrict__ a_src, const float* __restrict__ a_dst,
    float* __restrict__ s, float* __restrict__ d,
    int H, int C, int Cpair, int ldp)
{
    int node = blockIdx.x;
    int tid = threadIdx.x;
    int G = 256 / H;
    int h = tid / G;
    int cp = tid - h * G;
    float vs = 0.f, vd = 0.f;
    if (cp < Cpair) {
        uint_t p = xpb[(size_t)node * ldp + h * Cpair + cp];
        float f0 = bf_lo(p), f1 = bf_hi(p);
        int c = cp * 2;
        vs = f0 * a_src[h * C + c] + f1 * a_src[h * C + c + 1];
        vd = f0 * a_dst[h * C + c] + f1 * a_dst[h * C + c + 1];
    }
    __shared__ float rs[256];
    __shared__ float rd[256];
    rs[tid] = vs; rd[tid] = vd;
    __syncthreads();
    for (int off = G >> 1; off > 0; off >>= 1) {
        if (cp < off) { rs[tid] += rs[tid + off]; rd[tid] += rd[tid + off]; }
        __syncthreads();
    }
    if (cp == 0) { s[node * H + h] = rs[tid]; d[node * H + h] = rd[tid]; }
}

// ---------------------------------------------------------------------------
// scalar softmax over each dst's edge list: one wave per dst node.
// ---------------------------------------------------------------------------
template<int H>
__global__ __launch_bounds__(64) void edge_softmax_kernel(
    const float* __restrict__ s,     // [node][H]
    const float* __restrict__ dlog,  // [node][H]
    const int* __restrict__ offsets, const int* __restrict__ esrc,
    float* __restrict__ ew,          // [E][H] unnormalized exp weights
    float* __restrict__ wself,       // [node][H]
    float* __restrict__ zinv)        // [node][H]
{
    int dst = blockIdx.x;
    int lane = threadIdx.x;
    int e0 = offsets[dst], e1 = offsets[dst + 1];

    float dh[H], selfe[H], mh[H], zh[H];
#pragma unroll
    for (int h = 0; h < H; ++h) {
        dh[h] = dlog[dst * H + h];
        selfe[h] = lrelu(s[dst * H + h] + dh[h]);
        mh[h] = selfe[h];
        zh[h] = 0.f;
    }

    // pass 1: max
    for (int j = e0 + lane; j < e1; j += 64) {
        int src = esrc[j];
        if (H == 4) {
            float4 sv = ((const float4*)s)[src];
            mh[0] = fmaxf(mh[0], lrelu(sv.x + dh[0]));
            mh[1] = fmaxf(mh[1], lrelu(sv.y + dh[1]));
            mh[2] = fmaxf(mh[2], lrelu(sv.z + dh[2]));
            mh[3] = fmaxf(mh[3], lrelu(sv.w + dh[3]));
        } else {
#pragma unroll
            for (int h = 0; h < H; ++h)
                mh[h] = fmaxf(mh[h], lrelu(s[src * H + h] + dh[h]));
        }
    }
#pragma unroll
    for (int h = 0; h < H; ++h)
        for (int off = 32; off > 0; off >>= 1)
            mh[h] = fmaxf(mh[h], __shfl_xor(mh[h], off));

    // pass 2: w = exp(e - m), store, sum
    for (int j = e0 + lane; j < e1; j += 64) {
        int src = esrc[j];
        if (H == 4) {
            float4 sv = ((const float4*)s)[src];
            float w0 = __expf(lrelu(sv.x + dh[0]) - mh[0]);
            float w1 = __expf(lrelu(sv.y + dh[1]) - mh[1]);
            float w2 = __expf(lrelu(sv.z + dh[2]) - mh[2]);
            float w3 = __expf(lrelu(sv.w + dh[3]) - mh[3]);
            ((float4*)ew)[j] = make_float4(w0, w1, w2, w3);
            zh[0] += w0; zh[1] += w1; zh[2] += w2; zh[3] += w3;
        } else {
#pragma unroll
            for (int h = 0; h < H; ++h) {
                float w = __expf(lrelu(s[src * H + h] + dh[h]) - mh[h]);
                ew[(size_t)j * H + h] = w;
                zh[h] += w;
            }
        }
    }
#pragma unroll
    for (int h = 0; h < H; ++h)
        for (int off = 32; off > 0; off >>= 1)
            zh[h] += __shfl_xor(zh[h], off);

    if (lane == 0) {
#pragma unroll
        for (int h = 0; h < H; ++h) {
            float ws = __expf(selfe[h] - mh[h]);
            wself[dst * H + h] = ws;
            zinv[dst * H + h] = 1.0f / (zh[h] + ws);
        }
    }
}

// ---------------------------------------------------------------------------
// weighted gather-aggregate, wave-per-node, uint4 (16B/lane = 1KB/row/inst).
// xpb4: [node][64] uint4 (row = 512 bf16 = 1KB; layer-3 rows zero-padded).
// Each lane owns 8 consecutive channels. 4 waves (4 nodes) per block.
// ---------------------------------------------------------------------------
__device__ __forceinline__ void acc8(float* acc, uint4 q, float w) {
    acc[0] += w * bf_lo(q.x); acc[1] += w * bf_hi(q.x);
    acc[2] += w * bf_lo(q.y); acc[3] += w * bf_hi(q.y);
    acc[4] += w * bf_lo(q.z); acc[5] += w * bf_hi(q.z);
    acc[6] += w * bf_lo(q.w); acc[7] += w * bf_hi(q.w);
}

template<int H>
__global__ __launch_bounds__(256) void aggregate3_kernel(
    const uint4* __restrict__ xpb4,     // [node][64]
    const int* __restrict__ offsets, const int* __restrict__ esrc,
    const float* __restrict__ ew,       // [E][H]
    const float* __restrict__ wself,    // [node][H]
    const float* __restrict__ zinv,     // [node][H]
    const float* __restrict__ bias,     // [OUTC]
    float* __restrict__ out,            // [node][ldo]
    int OUTC, int ldo)
{
    int node = blockIdx.x * 4 + (threadIdx.x >> 6);
    if (node >= NNODES) return;
    int lane = threadIdx.x & 63;
    int h = (H == 4) ? (lane >> 4) : 0;   // 8 ch/lane, 128 ch/head

    float ws = wself[node * H + h];
    uint4 p = xpb4[(size_t)node * 64 + lane];
    float acc[8];
    acc[0] = ws * bf_lo(p.x); acc[1] = ws * bf_hi(p.x);
    acc[2] = ws * bf_lo(p.y); acc[3] = ws * bf_hi(p.y);
    acc[4] = ws * bf_lo(p.z); acc[5] = ws * bf_hi(p.z);
    acc[6] = ws * bf_lo(p.w); acc[7] = ws * bf_hi(p.w);

    int e0 = offsets[node], e1 = offsets[node + 1];
    int j = e0;
    for (; j + 3 < e1; j += 4) {
        int s0 = esrc[j], s1 = esrc[j + 1], s2 = esrc[j + 2], s3 = esrc[j + 3];
        float w0 = ew[(size_t)j * H + h];
        float w1 = ew[(size_t)(j + 1) * H + h];
        float w2 = ew[(size_t)(j + 2) * H + h];
        float w3 = ew[(size_t)(j + 3) * H + h];
        uint4 q0 = xpb4[(size_t)s0 * 64 + lane];
        uint4 q1 = xpb4[(size_t)s1 * 64 + lane];
        uint4 q2 = xpb4[(size_t)s2 * 64 + lane];
        uint4 q3 = xpb4[(size_t)s3 * 64 + lane];
        acc8(acc, q0, w0);
        acc8(acc, q1, w1);
        acc8(acc, q2, w2);
        acc8(acc, q3, w3);
    }
    for (; j < e1; ++j) {
        int s0 = esrc[j];
        float w0 = ew[(size_t)j * H + h];
        uint4 q0 = xpb4[(size_t)s0 * 64 + lane];
        acc8(acc, q0, w0);
    }

    float zi = zinv[node * H + h];
    int cbase = lane * 8;
    size_t ob = (size_t)node * ldo + cbase;
    if (cbase + 7 < OUTC) {
        float4 o0 = make_float4(acc[0] * zi + bias[cbase + 0], acc[1] * zi + bias[cbase + 1],
                                acc[2] * zi + bias[cbase + 2], acc[3] * zi + bias[cbase + 3]);
        float4 o1 = make_float4(acc[4] * zi + bias[cbase + 4], acc[5] * zi + bias[cbase + 5],
                                acc[6] * zi + bias[cbase + 6], acc[7] * zi + bias[cbase + 7]);
        *(float4*)(out + ob) = o0;
        *(float4*)(out + ob + 4) = o1;
    } else {
#pragma unroll
        for (int k = 0; k < 8; ++k) {
            int c = cbase + k;
            if (c < OUTC) out[ob + k] = acc[k] * zi + bias[c];
        }
    }
}

// ---------------------------------------------------------------------------
// BatchNorm (training-mode normalization, biased var) + ELU -> bf16
// ---------------------------------------------------------------------------
__global__ __launch_bounds__(512) void bn_stats_kernel(const float* __restrict__ h,
                                                       float* __restrict__ sums,
                                                       float* __restrict__ sumsq,
                                                       int Nrows, int Ncols) {
    int c = threadIdx.x;  // Ncols == 512 == blockDim
    float sm = 0.f, sq = 0.f;
    for (int r = blockIdx.x; r < Nrows; r += gridDim.x) {
        float v = h[(size_t)r * Ncols + c];
        sm += v;
        sq += v * v;
    }
    atomicAdd(&sums[c], sm);
    atomicAdd(&sumsq[c], sq);
}

__global__ __launch_bounds__(512) void bn_finalize_kernel(const float* __restrict__ sums,
                                                          const float* __restrict__ sumsq,
                                                          const float* __restrict__ gamma,
                                                          const float* __restrict__ beta,
                                                          float* __restrict__ scale,
                                                          float* __restrict__ shift,
                                                          int Nrows, int Ncols) {
    int c = threadIdx.x;
    if (c < Ncols) {
        float mu = sums[c] / (float)Nrows;
        float var = sumsq[c] / (float)Nrows - mu * mu;
        float sc = gamma[c] * rsqrtf(var + BN_EPS);
        scale[c] = sc;
        shift[c] = beta[c] - mu * sc;
    }
}

// h fp32 [N][512] -> hbf packed bf16 pairs [N][256]
__global__ void bn_apply_elu_bf16_kernel(const float* __restrict__ h,
                                         const float* __restrict__ scale,
                                         const float* __restrict__ shift,
                                         uint_t* __restrict__ hbf,
                                         int npairs) {
    int i = blockIdx.x * blockDim.x + threadIdx.x;
    if (i < npairs) {
        int c0 = (i & 255) * 2;   // Ncols = 512
        float2 hv = ((const float2*)h)[i];
        float v0 = hv.x * scale[c0]     + shift[c0];
        float v1 = hv.y * scale[c0 + 1] + shift[c0 + 1];
        v0 = (v0 > 0.f) ? v0 : (__expf(v0) - 1.0f);
        v1 = (v1 > 0.f) ? v1 : (__expf(v1) - 1.0f);
        hbf[i] = ((uint_t)f2bf(v1) << 16) | (uint_t)f2bf(v0);
    }
}

// ---------------------------------------------------------------------------
// launch
// ---------------------------------------------------------------------------
extern "C" void kernel_launch(void* const* d_in, const int* in_sizes, int n_in,
                              void* d_out, int out_size, void* d_ws, size_t ws_size,
                              hipStream_t stream) {
    const float* x      = (const float*)d_in[0];
    const int*   ei     = (const int*)d_in[1];
    const float* W1     = (const float*)d_in[2];
    const float* a_src1 = (const float*)d_in[3];
    const float* a_dst1 = (const float*)d_in[4];
    const float* b1     = (const float*)d_in[5];
    const float* g1     = (const float*)d_in[6];
    const float* be1    = (const float*)d_in[7];
    const float* W2     = (const float*)d_in[8];
    const float* a_src2 = (const float*)d_in[9];
    const float* a_dst2 = (const float*)d_in[10];
    const float* b2     = (const float*)d_in[11];
    const float* g2     = (const float*)d_in[12];
    const float* be2    = (const float*)d_in[13];
    const float* W3     = (const float*)d_in[14];
    const float* a_src3 = (const float*)d_in[15];
    const float* a_dst3 = (const float*)d_in[16];
    const float* b3     = (const float*)d_in[17];
    float* out = (float*)d_out;

    const int* e_src = ei;           // edge_index[0]
    const int* e_dst = ei + NEDGES;  // edge_index[1]

    // ---- workspace layout ----
    char* w = (char*)d_ws;
    // region 0: x_bf (25.6 MB), later reused as hbuf fp32 (20.48 MB) + ew (5.12 MB)
    ushort_t* x_bf = (ushort_t*)w;
    float*    hbuf = (float*)w;                               // alias after L1 GEMM
    float*    ew   = (float*)(w + (size_t)NNODES * HC_ * sizeof(float));  // tail 5.12 MB
    w += (size_t)NNODES * INF_ * sizeof(ushort_t);            // 25,600,000
    uint_t* xpb = (uint_t*)w;  w += (size_t)NNODES * HC_ * sizeof(ushort_t);   // 10,240,000
    uint_t* hbf = (uint_t*)w;  w += (size_t)NNODES * HC_ * sizeof(ushort_t);   // 10,240,000
    ushort_t* Wt1 = (ushort_t*)w; w += (size_t)INF_ * HC_ * sizeof(ushort_t);  // 1,310,720
    ushort_t* Wt2 = (ushort_t*)w; w += (size_t)HC_ * HC_ * sizeof(ushort_t);   //   524,288
    ushort_t* Wt3 = (ushort_t*)w; w += (size_t)HC_ * OUTF_ * sizeof(ushort_t); //   512,000
    float* s_log = (float*)w;  w += NNODES * HEADS_ * sizeof(float);
    float* d_log = (float*)w;  w += NNODES * HEADS_ * sizeof(float);
    float* wself = (float*)w;  w += NNODES * HEADS_ * sizeof(float);
    float* zinv  = (float*)w;  w += NNODES * HEADS_ * sizeof(float);
    float* bns   = (float*)w;  w += HC_ * sizeof(float);
    float* bnss  = (float*)w;  w += HC_ * sizeof(float);
    float* bnscale = (float*)w; w += HC_ * sizeof(float);
    float* bnshift = (float*)w; w += HC_ * sizeof(float);
    int* counts  = (int*)w;    w += NNODES * sizeof(int);
    int* offsets = (int*)w;    w += (NNODES + 1) * sizeof(int);
    int* cursor  = (int*)w;    w += NNODES * sizeof(int);
    int* esrc    = (int*)w;    w += NEDGES * sizeof(int);

    // ---- CSR build (once; shared by all 3 layers) ----
    zero_kernel<<<64, 256, 0, stream>>>((float*)counts, NNODES);
    count_kernel<<<(NEDGES + 255) / 256, 256, 0, stream>>>(e_dst, counts, NEDGES);
    scan_kernel<<<1, 1024, 0, stream>>>(counts, offsets, NNODES);
    copy_int_kernel<<<(NNODES + 255) / 256, 256, 0, stream>>>(offsets, cursor, NNODES);
    scatter_kernel<<<(NEDGES + 255) / 256, 256, 0, stream>>>(e_src, e_dst, cursor, esrc, NEDGES);

    // ---- bf16 conversions (x and transposed weights) ----
    {
        int nx = NNODES * INF_;
        conv_bf16_kernel<<<(nx + 255) / 256, 256, 0, stream>>>(x, x_bf, nx);
        int n1 = INF_ * HC_;
        transconv_kernel<<<(n1 + 255) / 256, 256, 0, stream>>>(W1, Wt1, INF_, HC_);
        int n2 = HC_ * HC_;
        transconv_kernel<<<(n2 + 255) / 256, 256, 0, stream>>>(W2, Wt2, HC_, HC_);
        int n3 = HC_ * OUTF_;
        transconv_kernel<<<(n3 + 255) / 256, 256, 0, stream>>>(W3, Wt3, HC_, OUTF_);
    }

    dim3 gb(256);
    dim3 gg1((HC_ + 63) / 64, (NNODES + 63) / 64);
    int aggGrid = (NNODES + 3) / 4;

    // ---- Layer 1 ----   (x_bf dead after this GEMM; hbuf/ew alias its region)
    gemm_bf16_kernel<<<gg1, gb, 0, stream>>>(x_bf, Wt1, nullptr, (ushort_t*)xpb, NNODES, INF_, HC_, HC_);
    logits_bf16_kernel<<<NNODES, 256, 0, stream>>>(xpb, a_src1, a_dst1, s_log, d_log, HEADS_, HID_, HID_ / 2, HC_ / 2);
    edge_softmax_kernel<HEADS_><<<NNODES, 64, 0, stream>>>(s_log, d_log, offsets, esrc, ew, wself, zinv);
    aggregate3_kernel<HEADS_><<<aggGrid, 256, 0, stream>>>((const uint4*)xpb, offsets, esrc, ew, wself, zinv, b1, hbuf, HC_, HC_);
    zero_kernel<<<4, 256, 0, stream>>>(bns, 2 * HC_);
    bn_stats_kernel<<<64, 512, 0, stream>>>(hbuf, bns, bnss, NNODES, HC_);
    bn_finalize_kernel<<<1, 512, 0, stream>>>(bns, bnss, g1, be1, bnscale, bnshift, NNODES, HC_);
    bn_apply_elu_bf16_kernel<<<(NNODES * 256 + 255) / 256, 256, 0, stream>>>(hbuf, bnscale, bnshift, hbf, NNODES * 256);

    // ---- Layer 2 ----
    gemm_bf16_kernel<<<gg1, gb, 0, stream>>>((const ushort_t*)hbf, Wt2, nullptr, (ushort_t*)xpb, NNODES, HC_, HC_, HC_);
    logits_bf16_kernel<<<NNODES, 256, 0, stream>>>(xpb, a_src2, a_dst2, s_log, d_log, HEADS_, HID_, HID_ / 2, HC_ / 2);
    edge_softmax_kernel<HEADS_><<<NNODES, 64, 0, stream>>>(s_log, d_log, offsets, esrc, ew, wself, zinv);
    aggregate3_kernel<HEADS_><<<aggGrid, 256, 0, stream>>>((const uint4*)xpb, offsets, esrc, ew, wself, zinv, b2, hbuf, HC_, HC_);
    zero_kernel<<<4, 256, 0, stream>>>(bns, 2 * HC_);
    bn_stats_kernel<<<64, 512, 0, stream>>>(hbuf, bns, bnss, NNODES, HC_);
    bn_finalize_kernel<<<1, 512, 0, stream>>>(bns, bnss, g2, be2, bnscale, bnshift, NNODES, HC_);
    bn_apply_elu_bf16_kernel<<<(NNODES * 256 + 255) / 256, 256, 0, stream>>>(hbuf, bnscale, bnshift, hbf, NNODES * 256);

    // ---- Layer 3 (H=1, C=500; xp padded to 512-ch stride; output -> d_out) ----
    dim3 gg3((HC_ + 63) / 64, (NNODES + 63) / 64);   // cover full 512-wide padded C
    gemm_bf16_kernel<<<gg3, gb, 0, stream>>>((const ushort_t*)hbf, Wt3, nullptr, (ushort_t*)xpb, NNODES, HC_, OUTF_, HC_);
    logits_bf16_kernel<<<NNODES, 256, 0, stream>>>(xpb, a_src3, a_dst3, s_log, d_log, 1, OUTF_, OUTF_ / 2, HC_ / 2);
    edge_softmax_kernel<1><<<NNODES, 64, 0, stream>>>(s_log, d_log, offsets, esrc, ew, wself, zinv);
    aggregate3_kernel<1><<<aggGrid, 256, 0, stream>>>((const uint4*)xpb, offsets, esrc, ew, wself, zinv, b3, out, OUTF_, OUTF_);
}